// Round 8
// baseline (269.066 us; speedup 1.0000x reference)
//
#include <hip/hip_runtime.h>

// Correlation layer via 4x4-patch bf16 MFMA, two-pass (gfx950).
// out[b, dy*9+dx, y, x] = sum_c f1[b,c,y,x] * f2[b,c,y+dy-4,x+dx-4]
//
// R8: A-tile = 4x4 px patch; B-tiles = 4x4 patches at offsets (4i-4,4j-4),
// i,j in 0..2 (they tile the 12x12 neighborhood exactly). Each (dy,dx) pair
// appears exactly once across the 9 MFMAs: dy = 4i + (n>>2) - (m>>2),
// dx = 4j + (n&3) - (m&3). 56% useful MFMA products (vs 28% for 16x1 tiles),
// 9 B-loads + 9 MFMAs per chunk, and all 81 displacements complete in one
// wave -> no cross-dy refetch amplification.
//  - pass 1 (unchanged R6): f2 -> w2 [b][c/8][y'=72][x'=144][c%8] bf16,
//    zero halos baked in (42.5 MB in d_ws).
//  - pass 2: block = 128 thr = 2 waves = channel halves of one A-patch;
//    f1 packed in-kernel (8 dwords + 4 packs per chunk); 1 LDS reduce.

namespace {
constexpr int B_ = 8, C_ = 256, H_ = 64, W_ = 128;
constexpr int SIDE = 9, ND = 81, PAD = 4;
constexpr int HW = H_ * W_;
constexpr int CB = 32;              // channel-blocks of 8
constexpr int HP = 72, WP = 144;    // padded f2 dims (y' = y+dy, x' = x+4)
constexpr size_t NW2 = (size_t)B_ * CB * HP * WP;   // uint4 count, 2,654,208
constexpr size_t WS_BYTES = NW2 * 16;               // 42.5 MB
}

typedef __attribute__((ext_vector_type(8))) short short8;
typedef __attribute__((ext_vector_type(4))) float float4v;

__device__ __forceinline__ unsigned bf16rne(float f) {
  unsigned u = __float_as_uint(f);
  return (u + 0x7fffu + ((u >> 16) & 1u)) >> 16;
}
__device__ __forceinline__ unsigned packbf2(float lo, float hi) {
  return bf16rne(lo) | (bf16rne(hi) << 16);
}

// ---------------- pass 1: f2 fp32 -> padded fragment-ready bf16 ----------------
__global__ __launch_bounds__(256)
void cvt_f2(const float* __restrict__ f2, uint4* __restrict__ bws) {
  const int tid = blockIdx.x * 256 + threadIdx.x;
  const int xq = tid % (WP / 4);        // px-quad 0..35
  int r = tid / (WP / 4);
  const int yp = r % HP;
  r /= HP;
  const int cb = r % CB;
  const int b = r / CB;

  uint4 o[4] = {};
  const int yg = yp - PAD;
  const int x = xq * 4 - PAD;           // pad quads (xq==0, xq>=33) fully OOB
  if (yg >= 0 && yg < H_ && x >= 0 && x + 3 < W_) {
    const float* s = f2 + ((size_t)(b * C_ + cb * 8) * H_ + yg) * W_ + x;
    float vv[8][4];
#pragma unroll
    for (int e = 0; e < 8; ++e) {
      const float4 t = *(const float4*)(s + (size_t)e * HW);
      vv[e][0] = t.x; vv[e][1] = t.y; vv[e][2] = t.z; vv[e][3] = t.w;
    }
#pragma unroll
    for (int p = 0; p < 4; ++p) {
      o[p].x = packbf2(vv[0][p], vv[1][p]);
      o[p].y = packbf2(vv[2][p], vv[3][p]);
      o[p].z = packbf2(vv[4][p], vv[5][p]);
      o[p].w = packbf2(vv[6][p], vv[7][p]);
    }
  }
  uint4* d = bws + ((size_t)(b * CB + cb) * HP + yp) * WP + xq * 4;
#pragma unroll
  for (int p = 0; p < 4; ++p) d[p] = o[p];
}

// ---------------- pass 2: 4x4-patch MFMA ----------------
__global__ __launch_bounds__(128, 4)
void corr_mfma(const float* __restrict__ f1, const uint4* __restrict__ w2,
               float* __restrict__ out) {
  __shared__ float red[36 * 64];        // 9216 B

  const int t = threadIdx.x;
  const int lane = t & 63;
  const int cs = t >> 6;                // channel half: 0 -> c 0..127, 1 -> 128..255
  const int v = lane & 15;              // fragment pixel index
  const int q = lane >> 4;              // k-quad / C-row-group
  const int Ax = blockIdx.x * 4;        // A-patch origin
  const int Ay = blockIdx.y * 4;
  const int b = blockIdx.z;

  const int ya = Ay + (v >> 2);         // this lane's A pixel (A-frag m = v)
  const int xa = Ax + (v & 3);

  float4v acc[9];
#pragma unroll
  for (int k = 0; k < 9; ++k) acc[k] = (float4v){0.f, 0.f, 0.f, 0.f};

  // A: f1[b, cs*128 + ch*32 + 8q + j, ya, xa]
  const float* a0 =
      f1 + ((size_t)(b * C_ + cs * 128 + q * 8) * H_ + ya) * W_ + xa;
  // B: w2[((b*CB + cs*16 + ch*4 + q)*HP + Ay + 4i + (v>>2))*WP + Ax + 4j + (v&3)]
  const uint4* b0 =
      w2 + ((size_t)(b * CB + cs * 16 + q) * HP + Ay + (v >> 2)) * WP + Ax + (v & 3);

  for (int ch = 0; ch < 4; ++ch) {
    uint4 Bv[9];
    const uint4* bp = b0 + (size_t)(ch * 4) * (HP * WP);
#pragma unroll
    for (int i = 0; i < 3; ++i)
#pragma unroll
      for (int j = 0; j < 3; ++j)
        Bv[3 * i + j] = bp[(size_t)(4 * i) * WP + 4 * j];

    float av[8];
#pragma unroll
    for (int j = 0; j < 8; ++j) av[j] = a0[(size_t)(ch * 32 + j) * HW];
    uint4 afu;
    afu.x = packbf2(av[0], av[1]);
    afu.y = packbf2(av[2], av[3]);
    afu.z = packbf2(av[4], av[5]);
    afu.w = packbf2(av[6], av[7]);
    const short8 af = __builtin_bit_cast(short8, afu);

#pragma unroll
    for (int k = 0; k < 9; ++k)
      acc[k] = __builtin_amdgcn_mfma_f32_16x16x32_bf16(
          af, __builtin_bit_cast(short8, Bv[k]), acc[k], 0, 0, 0);
  }

  // ---- combine channel halves: wave1 -> LDS -> wave0 (stride-1, conflict-free)
  if (cs == 1) {
#pragma unroll
    for (int k = 0; k < 9; ++k)
#pragma unroll
      for (int r = 0; r < 4; ++r) red[(k * 4 + r) * 64 + lane] = acc[k][r];
  }
  __syncthreads();
  if (cs == 0) {
#pragma unroll
    for (int k = 0; k < 9; ++k)
#pragma unroll
      for (int r = 0; r < 4; ++r) acc[k][r] += red[(k * 4 + r) * 64 + lane];

    // ---- epilogue: lane holds C[m=4q+r][n=v] for B-block (i,j).
    // dy = 4i + (n>>2) - (m>>2), dx = 4j + (n&3) - (m&3); each valid (dy,dx)
    // lands exactly once across the 9 blocks.
#pragma unroll
    for (int i = 0; i < 3; ++i)
#pragma unroll
      for (int j = 0; j < 3; ++j)
#pragma unroll
        for (int r = 0; r < 4; ++r) {
          const int m = q * 4 + r;
          const int dy = 4 * i + (v >> 2) - (m >> 2);
          const int dx = 4 * j + (v & 3) - (m & 3);
          if (dy >= 0 && dy <= 8 && dx >= 0 && dx <= 8) {
            out[((size_t)(b * ND + dy * SIDE + dx) * H_ + Ay + (m >> 2)) * W_ +
                Ax + (m & 3)] = acc[3 * i + j][r];
          }
        }
  }
}

// ---------------- fallback (R5 kernel) if ws_size is too small ----------------
namespace fb {
constexpr int PXS = 20, F2PX = 80, F1PX = 64, KC = 32, NCH = C_ / KC;
constexpr int F2U = SIDE * (F2PX / 4) * (KC / 2);
constexpr int F1U = (F1PX / 4) * (KC / 2);
constexpr int NU = F2U + F1U;
}

__global__ __launch_bounds__(512, 4)
void corr_fallback(const float* __restrict__ f1, const float* __restrict__ f2,
                   float* __restrict__ out) {
  using namespace fb;
  __shared__ __align__(16) unsigned f2s[SIDE * F2PX * PXS];
  __shared__ __align__(16) unsigned f1s[F1PX * PXS];

  const int t = threadIdx.x;
  const int bx = blockIdx.x, by = blockIdx.y, b = blockIdx.z;
  const int x0B = bx * 64;
  const int lane = t & 63, wv = t >> 6;
  const int wt = wv >> 1, half = wv & 1;
  const int dyb = half * 5, ndy = 5 - half;
  const int v = lane & 15, q = lane >> 4;

  float4v acc0[5], acc1[5];
#pragma unroll
  for (int i = 0; i < 5; ++i) {
    acc0[i] = (float4v){0.f, 0.f, 0.f, 0.f};
    acc1[i] = (float4v){0.f, 0.f, 0.f, 0.f};
  }
  const float* __restrict__ f1b = f1 + (size_t)b * C_ * HW;
  const float* __restrict__ f2b = f2 + (size_t)b * C_ * HW;

  for (int ch = 0; ch < NCH; ++ch) {
    const int c0 = ch * KC;
    if (ch) __syncthreads();
    for (int u = t; u < NU; u += 512) {
      if (u < F2U) {
        const int cp = u & 15;
        const int rp = u >> 4;
        const int pxq = rp % 20;
        const int r = rp / 20;
        const int yg = by + r - PAD;
        const int xb = x0B - PAD + pxq * 4;
        float4 va = make_float4(0.f, 0.f, 0.f, 0.f), vb = va;
        if (yg >= 0 && yg < H_ && xb >= 0 && xb <= W_ - 4) {
          const float* p = f2b + ((size_t)(c0 + 2 * cp) * H_ + yg) * W_ + xb;
          va = *(const float4*)p;
          vb = *(const float4*)(p + HW);
        }
        unsigned* d = &f2s[(r * F2PX + pxq * 4) * PXS + cp];
        d[0 * PXS] = packbf2(va.x, vb.x);
        d[1 * PXS] = packbf2(va.y, vb.y);
        d[2 * PXS] = packbf2(va.z, vb.z);
        d[3 * PXS] = packbf2(va.w, vb.w);
      } else {
        const int u2 = u - F2U;
        const int cp = u2 & 15;
        const int pxq = u2 >> 4;
        const float* p = f1b + ((size_t)(c0 + 2 * cp) * H_ + by) * W_ + x0B + pxq * 4;
        const float4 va = *(const float4*)p;
        const float4 vb = *(const float4*)(p + HW);
        unsigned* d = &f1s[(pxq * 4) * PXS + cp];
        d[0 * PXS] = packbf2(va.x, vb.x);
        d[1 * PXS] = packbf2(va.y, vb.y);
        d[2 * PXS] = packbf2(va.z, vb.z);
        d[3 * PXS] = packbf2(va.w, vb.w);
      }
    }
    __syncthreads();

    const short8 af =
        __builtin_bit_cast(short8, *(const uint4*)&f1s[(16 * wt + v) * PXS + 4 * q]);
#pragma unroll
    for (int i = 0; i < 5; ++i) {
      if (i < ndy) {
        const int dy = dyb + i;
        const unsigned* fbp = &f2s[(dy * F2PX + 16 * wt + v) * PXS + 4 * q];
        const short8 b0 = __builtin_bit_cast(short8, *(const uint4*)fbp);
        const short8 b1 = __builtin_bit_cast(short8, *(const uint4*)(fbp + 16 * PXS));
        acc0[i] = __builtin_amdgcn_mfma_f32_16x16x32_bf16(af, b0, acc0[i], 0, 0, 0);
        acc1[i] = __builtin_amdgcn_mfma_f32_16x16x32_bf16(af, b1, acc1[i], 0, 0, 0);
      }
    }
  }
#pragma unroll
  for (int i = 0; i < 5; ++i) {
    if (i < ndy) {
      const int dy = dyb + i;
#pragma unroll
      for (int r = 0; r < 4; ++r) {
        const int m = q * 4 + r;
        const int x = x0B + 16 * wt + m;
        const int dx0 = v - m;
        if (dx0 >= 0 && dx0 <= 8)
          out[(((size_t)b * ND + dy * SIDE + dx0) * H_ + by) * W_ + x] = acc0[i][r];
        const int dx1 = v - m + 16;
        if (dx1 <= 8)
          out[(((size_t)b * ND + dy * SIDE + dx1) * H_ + by) * W_ + x] = acc1[i][r];
      }
    }
  }
}

extern "C" void kernel_launch(void* const* d_in, const int* in_sizes, int n_in,
                              void* d_out, int out_size, void* d_ws, size_t ws_size,
                              hipStream_t stream) {
  const float* f1 = (const float*)d_in[0];
  const float* f2 = (const float*)d_in[1];
  float* out = (float*)d_out;

  if (ws_size >= WS_BYTES) {
    uint4* w2 = (uint4*)d_ws;
    const int n1 = (int)(NW2 / 4);                 // 663552 threads, 4 uint4 each
    cvt_f2<<<dim3(n1 / 256), 256, 0, stream>>>(f2, w2);
    corr_mfma<<<dim3(W_ / 4, H_ / 4, B_), 128, 0, stream>>>(f1, w2, out);
  } else {
    corr_fallback<<<dim3(2, H_, B_), 512, 0, stream>>>(f1, f2, out);
  }
}

// Round 10
// 213.972 us; speedup vs baseline: 1.2575x; 1.2575x over previous
//
#include <hip/hip_runtime.h>

// Correlation layer via banded bf16 MFMA, two-pass (gfx950).
// out[b, dy*9+dx, y, x] = sum_c f1[b,c,y,x] * f2[b,c,y+dy-4,x+dx-4]
//
// R9 (resubmit — previous round hit GPUAcquisitionTimeout, no data):
// revert R8's 4x4 patches (FETCH 366MB == issued bytes: zero cache
// capture). Back to R6's 16x1 banded tiles (85% cache capture), plus:
//  - XCD swizzle: 1-D grids, b = id&7 -> all blocks of batch b land on one
//    XCD (round-robin dispatch); w2 slice/batch = 5.3MB ~ L2 (4MB). cvt is
//    swizzled identically so its dirty w2 lines sit in the right L2.
//  - pass2 inner order: y sweeps consecutively per XCD (k = y*4+bx), so
//    successive blocks share 8/9 of their w2 rows.
//  - cvt: one uint4 per thread, coalesced loads and stores.
//  - A-fragments packed in-kernel from fp32 f1 (R7 pre-convert cost more in
//    pass-1 traffic + drain than it saved in pass 2).

namespace {
constexpr int B_ = 8, C_ = 256, H_ = 64, W_ = 128;
constexpr int SIDE = 9, ND = 81, PAD = 4;
constexpr int HW = H_ * W_;
constexpr int CB = 32;              // channel-blocks of 8
constexpr int HP = 72, WP = 144;    // padded f2 dims (y' = y+dy, x' = x+4)
constexpr size_t NW2 = (size_t)B_ * CB * HP * WP;   // 2,654,208 uint4
constexpr size_t WS_BYTES = NW2 * 16;               // 42.5 MB
constexpr int PERB = (int)(NW2 / B_);               // 331,776 uint4 per batch
}

typedef __attribute__((ext_vector_type(8))) short short8;
typedef __attribute__((ext_vector_type(4))) float float4v;

__device__ __forceinline__ unsigned bf16rne(float f) {
  unsigned u = __float_as_uint(f);
  return (u + 0x7fffu + ((u >> 16) & 1u)) >> 16;
}
__device__ __forceinline__ unsigned packbf2(float lo, float hi) {
  return bf16rne(lo) | (bf16rne(hi) << 16);
}

// ------- pass 1: f2 fp32 -> padded fragment-ready bf16, XCD-swizzled -------
__global__ __launch_bounds__(256)
void cvt_f2(const float* __restrict__ f2, uint4* __restrict__ w2) {
  const int id = blockIdx.x;
  const int b = id & 7;                       // XCD pin
  const int e = (id >> 3) * 256 + threadIdx.x;  // 0..PERB-1
  const int xp = e % WP;
  const int r = e / WP;
  const int yp = r % HP;
  const int cb = r / HP;                      // 0..31

  const int yg = yp - PAD, xg = xp - PAD;
  uint4 o = {0u, 0u, 0u, 0u};
  if (yg >= 0 && yg < H_ && xg >= 0 && xg < W_) {
    const float* s = f2 + ((size_t)(b * C_ + cb * 8) * H_ + yg) * W_ + xg;
    o.x = packbf2(s[0 * HW], s[1 * HW]);
    o.y = packbf2(s[2 * HW], s[3 * HW]);
    o.z = packbf2(s[4 * HW], s[5 * HW]);
    o.w = packbf2(s[6 * HW], s[7 * HW]);
  }
  w2[(size_t)b * PERB + e] = o;
}

// ------- pass 2: banded MFMA, XCD-swizzled, fragments from global ----------
__global__ __launch_bounds__(256, 4)
void corr_mfma(const float* __restrict__ f1, const uint4* __restrict__ w2,
               float* __restrict__ out) {
  const int id = blockIdx.x;
  const int b = id & 7;                       // XCD pin (same as cvt)
  const int k = id >> 3;                      // 0..255
  const int bx = k & 3;                       // x quarter
  const int y = k >> 2;                       // consecutive y per XCD

  const int t = threadIdx.x;
  const int lane = t & 63;
  const int wv = t >> 6;                      // 0..3
  const int jm = bx * 2 + (wv >> 1);          // M-tile 0..7 (x = 16*jm..)
  const int half = wv & 1;                    // dy half: 0 -> dy 0..4, 1 -> 5..8
  const int v = lane & 15;                    // fragment pixel index
  const int q = lane >> 4;                    // k-quad / C-row-group
  const int dyb = half * 5;
  const int ndy = 5 - half;

  float4v acc0[5], acc1[5];
#pragma unroll
  for (int i = 0; i < 5; ++i) {
    acc0[i] = (float4v){0.f, 0.f, 0.f, 0.f};
    acc1[i] = (float4v){0.f, 0.f, 0.f, 0.f};
  }

  // A: f1[b, ch*32 + q*8 + j, y, 16jm + v]
  const float* a_base =
      f1 + ((size_t)(b * C_ + q * 8) * H_ + y) * W_ + 16 * jm + v;
  // B: w2[(b*CB + ch*4 + q) plane, row y+dy, col 16*jm + v] (+16 for tile1)
  const uint4* b_base =
      w2 + ((size_t)(b * CB + q) * HP + (y + dyb)) * WP + 16 * jm + v;

#pragma unroll
  for (int ch = 0; ch < 8; ++ch) {
    uint4 Bv[10];
    const uint4* bc = b_base + (size_t)(ch * 4) * (HP * WP);
#pragma unroll
    for (int i = 0; i < 5; ++i) {
      if (i < ndy) {
        Bv[2 * i] = bc[(size_t)i * WP];
        Bv[2 * i + 1] = bc[(size_t)i * WP + 16];
      }
    }
    float av[8];
#pragma unroll
    for (int j = 0; j < 8; ++j) av[j] = a_base[(size_t)(ch * 32 + j) * HW];
    uint4 afu;
    afu.x = packbf2(av[0], av[1]);
    afu.y = packbf2(av[2], av[3]);
    afu.z = packbf2(av[4], av[5]);
    afu.w = packbf2(av[6], av[7]);
    const short8 af = __builtin_bit_cast(short8, afu);

#pragma unroll
    for (int i = 0; i < 5; ++i) {
      if (i < ndy) {
        acc0[i] = __builtin_amdgcn_mfma_f32_16x16x32_bf16(
            af, __builtin_bit_cast(short8, Bv[2 * i]), acc0[i], 0, 0, 0);
        acc1[i] = __builtin_amdgcn_mfma_f32_16x16x32_bf16(
            af, __builtin_bit_cast(short8, Bv[2 * i + 1]), acc1[i], 0, 0, 0);
      }
    }
  }

  // Epilogue: C/D col n = v, row m = q*4+reg. tile0: dx = n-m in [0,8];
  // tile1: dx = n-m+16 in [1,8]. Each output element written exactly once.
#pragma unroll
  for (int i = 0; i < 5; ++i) {
    if (i < ndy) {
      const int dy = dyb + i;
#pragma unroll
      for (int r = 0; r < 4; ++r) {
        const int m = q * 4 + r;
        const int x = 16 * jm + m;
        const int dx0 = v - m;
        if (dx0 >= 0 && dx0 <= 8)
          out[(((size_t)b * ND + dy * SIDE + dx0) * H_ + y) * W_ + x] = acc0[i][r];
        const int dx1 = v - m + 16;
        if (dx1 <= 8)
          out[(((size_t)b * ND + dy * SIDE + dx1) * H_ + y) * W_ + x] = acc1[i][r];
      }
    }
  }
}

// ---------------- fallback (R5 kernel) if ws_size is too small ----------------
namespace fb {
constexpr int PXS = 20, F2PX = 80, F1PX = 64, KC = 32, NCH = C_ / KC;
constexpr int F2U = SIDE * (F2PX / 4) * (KC / 2);
constexpr int F1U = (F1PX / 4) * (KC / 2);
constexpr int NU = F2U + F1U;
}

__global__ __launch_bounds__(512, 4)
void corr_fallback(const float* __restrict__ f1, const float* __restrict__ f2,
                   float* __restrict__ out) {
  using namespace fb;
  __shared__ __align__(16) unsigned f2s[SIDE * F2PX * PXS];
  __shared__ __align__(16) unsigned f1s[F1PX * PXS];

  const int t = threadIdx.x;
  const int bx = blockIdx.x, by = blockIdx.y, b = blockIdx.z;
  const int x0B = bx * 64;
  const int lane = t & 63, wv = t >> 6;
  const int wt = wv >> 1, half = wv & 1;
  const int dyb = half * 5, ndy = 5 - half;
  const int v = lane & 15, q = lane >> 4;

  float4v acc0[5], acc1[5];
#pragma unroll
  for (int i = 0; i < 5; ++i) {
    acc0[i] = (float4v){0.f, 0.f, 0.f, 0.f};
    acc1[i] = (float4v){0.f, 0.f, 0.f, 0.f};
  }
  const float* __restrict__ f1b = f1 + (size_t)b * C_ * HW;
  const float* __restrict__ f2b = f2 + (size_t)b * C_ * HW;

  for (int ch = 0; ch < NCH; ++ch) {
    const int c0 = ch * KC;
    if (ch) __syncthreads();
    for (int u = t; u < NU; u += 512) {
      if (u < F2U) {
        const int cp = u & 15;
        const int rp = u >> 4;
        const int pxq = rp % 20;
        const int r = rp / 20;
        const int yg = by + r - PAD;
        const int xb = x0B - PAD + pxq * 4;
        float4 va = make_float4(0.f, 0.f, 0.f, 0.f), vb = va;
        if (yg >= 0 && yg < H_ && xb >= 0 && xb <= W_ - 4) {
          const float* p = f2b + ((size_t)(c0 + 2 * cp) * H_ + yg) * W_ + xb;
          va = *(const float4*)p;
          vb = *(const float4*)(p + HW);
        }
        unsigned* d = &f2s[(r * F2PX + pxq * 4) * PXS + cp];
        d[0 * PXS] = packbf2(va.x, vb.x);
        d[1 * PXS] = packbf2(va.y, vb.y);
        d[2 * PXS] = packbf2(va.z, vb.z);
        d[3 * PXS] = packbf2(va.w, vb.w);
      } else {
        const int u2 = u - F2U;
        const int cp = u2 & 15;
        const int pxq = u2 >> 4;
        const float* p = f1b + ((size_t)(c0 + 2 * cp) * H_ + by) * W_ + x0B + pxq * 4;
        const float4 va = *(const float4*)p;
        const float4 vb = *(const float4*)(p + HW);
        unsigned* d = &f1s[(pxq * 4) * PXS + cp];
        d[0 * PXS] = packbf2(va.x, vb.x);
        d[1 * PXS] = packbf2(va.y, vb.y);
        d[2 * PXS] = packbf2(va.z, vb.z);
        d[3 * PXS] = packbf2(va.w, vb.w);
      }
    }
    __syncthreads();

    const short8 af =
        __builtin_bit_cast(short8, *(const uint4*)&f1s[(16 * wt + v) * PXS + 4 * q]);
#pragma unroll
    for (int i = 0; i < 5; ++i) {
      if (i < ndy) {
        const int dy = dyb + i;
        const unsigned* fbp = &f2s[(dy * F2PX + 16 * wt + v) * PXS + 4 * q];
        const short8 b0 = __builtin_bit_cast(short8, *(const uint4*)fbp);
        const short8 b1 = __builtin_bit_cast(short8, *(const uint4*)(fbp + 16 * PXS));
        acc0[i] = __builtin_amdgcn_mfma_f32_16x16x32_bf16(af, b0, acc0[i], 0, 0, 0);
        acc1[i] = __builtin_amdgcn_mfma_f32_16x16x32_bf16(af, b1, acc1[i], 0, 0, 0);
      }
    }
  }
#pragma unroll
  for (int i = 0; i < 5; ++i) {
    if (i < ndy) {
      const int dy = dyb + i;
#pragma unroll
      for (int r = 0; r < 4; ++r) {
        const int m = q * 4 + r;
        const int x = x0B + 16 * wt + m;
        const int dx0 = v - m;
        if (dx0 >= 0 && dx0 <= 8)
          out[(((size_t)b * ND + dy * SIDE + dx0) * H_ + by) * W_ + x] = acc0[i][r];
        const int dx1 = v - m + 16;
        if (dx1 <= 8)
          out[(((size_t)b * ND + dy * SIDE + dx1) * H_ + by) * W_ + x] = acc1[i][r];
      }
    }
  }
}

extern "C" void kernel_launch(void* const* d_in, const int* in_sizes, int n_in,
                              void* d_out, int out_size, void* d_ws, size_t ws_size,
                              hipStream_t stream) {
  const float* f1 = (const float*)d_in[0];
  const float* f2 = (const float*)d_in[1];
  float* out = (float*)d_out;

  if (ws_size >= WS_BYTES) {
    uint4* w2 = (uint4*)d_ws;
    cvt_f2<<<dim3((int)(NW2 / 256)), 256, 0, stream>>>(f2, w2);      // 10368 blocks
    corr_mfma<<<dim3(2048), 256, 0, stream>>>(f1, w2, out);          // 1-D, swizzled
  } else {
    corr_fallback<<<dim3(2, H_, B_), 512, 0, stream>>>(f1, f2, out);
  }
}